// Round 5
// baseline (404.419 us; speedup 1.0000x reference)
//
#include <hip/hip_runtime.h>
#include <hip/hip_bf16.h>
#include <cstdint>

#define EMB    768
#define NHEADS 12
#define HDIM   64
#define SEQ    1024
#define BATCH  8
#define MROWS  (BATCH*SEQ)   /* 8192 */
#define FFN    3072
#define W2E    (EMB*EMB)     /* 589824 */
#define W4E    (FFN*EMB)     /* 2359296 */

typedef __bf16 bf16_t;
typedef bf16_t bf16x8 __attribute__((ext_vector_type(8)));
typedef float  f32x4  __attribute__((ext_vector_type(4)));

__device__ __forceinline__ float b2f(unsigned short u) {
    union { unsigned int i; float f; } t; t.i = ((unsigned int)u) << 16; return t.f;
}
__device__ __forceinline__ unsigned short f2b(float f) {
    union { float f; unsigned int i; } t; t.f = f;
    unsigned int lsb = (t.i >> 16) & 1u;
    t.i += 0x7fffu + lsb;
    return (unsigned short)(t.i >> 16);
}
// raw v_exp_f32 (exp2)
__device__ __forceinline__ float fexp2(float x) {
#if defined(__has_builtin)
#if __has_builtin(__builtin_amdgcn_exp2f)
    return __builtin_amdgcn_exp2f(x);
#else
    return exp2f(x);
#endif
#else
    return exp2f(x);
#endif
}
__device__ __forceinline__ float frcp(float x) {
#if defined(__has_builtin)
#if __has_builtin(__builtin_amdgcn_rcpf)
    return __builtin_amdgcn_rcpf(x);
#else
    return 1.f / x;
#endif
#else
    return 1.f / x;
#endif
}
// fast tanh-gelu in exp2 space: gelu(x) = x * sigmoid(2c(x + 0.044715x^3))
//   = x / (1 + exp2(-(2c*log2e)(x + 0.044715x^3)))
// constants: 2c*log2e = 2.3022082, *0.044715 = 0.10294823
__device__ __forceinline__ float gelu_f(float x) {
    float x2 = x * x;
    float u  = x * __builtin_fmaf(x2, -0.10294823f, -2.3022082f);
    return x * frcp(1.f + fexp2(u));
}

#if defined(__has_builtin)
#if __has_builtin(__builtin_amdgcn_global_load_lds)
#define HAS_GLL 1
#endif
#endif
#ifndef HAS_GLL
#define HAS_GLL 0
#endif

__device__ __forceinline__ void gll16(const unsigned short* g, unsigned short* lds_wave_base) {
#if HAS_GLL
    __builtin_amdgcn_global_load_lds(
        (const __attribute__((address_space(1))) unsigned int*)g,
        (__attribute__((address_space(3))) unsigned int*)lds_wave_base, 16, 0, 0);
#endif
}
// staging helper: async global->LDS when available, manual 16B copy otherwise
__device__ __forceinline__ void stage16(const unsigned short* g, unsigned short* lds_wave_base, int lane) {
#if HAS_GLL
    __builtin_amdgcn_global_load_lds(
        (const __attribute__((address_space(1))) unsigned int*)g,
        (__attribute__((address_space(3))) unsigned int*)lds_wave_base, 16, 0, 0);
#else
    *reinterpret_cast<int4*>(lds_wave_base + lane * 8) = *reinterpret_cast<const int4*>(g);
#endif
}

__device__ __forceinline__ int4 load8(const void* src, size_t eoff, bool f32) {
    if (f32) {
        const float4* p = reinterpret_cast<const float4*>((const float*)src + eoff);
        float4 a = p[0], b = p[1];
        union { unsigned short u[8]; int4 v; } r;
        r.u[0] = f2b(a.x); r.u[1] = f2b(a.y); r.u[2] = f2b(a.z); r.u[3] = f2b(a.w);
        r.u[4] = f2b(b.x); r.u[5] = f2b(b.y); r.u[6] = f2b(b.z); r.u[7] = f2b(b.w);
        return r.v;
    }
    return *reinterpret_cast<const int4*>((const unsigned short*)src + eoff);
}
__device__ __forceinline__ float4 load4f(const void* src, size_t eoff, bool f32) {
    if (f32) return *reinterpret_cast<const float4*>((const float*)src + eoff);
    ushort4 u = *reinterpret_cast<const ushort4*>((const unsigned short*)src + eoff);
    float4 r; r.x = b2f(u.x); r.y = b2f(u.y); r.z = b2f(u.z); r.w = b2f(u.w);
    return r;
}

// ---------------- dtype probe: one block per input ------------------------
struct DetectArgs { const unsigned short* p[11]; int n[11]; };

__global__ __launch_bounds__(256) void detect_all(DetectArgs a, int* __restrict__ flags) {
    __shared__ int cnt;
    if (threadIdx.x == 0) cnt = 0;
    __syncthreads();
    const unsigned short* src = a.p[blockIdx.x];
    int npairs = a.n[blockIdx.x] / 2;
    if (npairs > 4096) npairs = 4096;
    int local = 0;
    for (int p = threadIdx.x; p < npairs; p += 256) {
        unsigned short u0 = src[2 * p], u1 = src[2 * p + 1];
        int e0 = (u0 >> 7) & 0xFF;
        bool insane0 = (e0 == 0xFF) || (u0 != 0 && (e0 < 96 || e0 > 159));
        bool zpat    = (u0 == 0 && u1 != 0);
        if (insane0 || zpat) ++local;
    }
    atomicAdd(&cnt, local);
    __syncthreads();
    if (threadIdx.x == 0) flags[blockIdx.x] = (cnt * 8 > npairs) ? 1 : 0;
}

// ---------------- adaptive convert (middle tier) --------------------------
__global__ __launch_bounds__(256) void cvt_adapt(
        const void* __restrict__ src, unsigned short* __restrict__ dst,
        int n, const int* __restrict__ flag) {
    int i = blockIdx.x * 256 + threadIdx.x;
    if (i * 4 >= n) return;
    if (*flag) {
        float4 f = reinterpret_cast<const float4*>(src)[i];
        ushort4 o;
        o.x = f2b(f.x); o.y = f2b(f.y); o.z = f2b(f.z); o.w = f2b(f.w);
        reinterpret_cast<ushort4*>(dst)[i] = o;
    } else {
        reinterpret_cast<ushort4*>(dst)[i] = reinterpret_cast<const ushort4*>(src)[i];
    }
}

// ---------------- fused weight convert: all 6 weights, one launch ---------
struct CvtArgs {
    const void* src[6];
    unsigned short* dst[6];
    int n[6];
    int blkoff[7];
    const int* F;
    int fidx[6];
};
__global__ __launch_bounds__(256) void cvt_weights(CvtArgs a) {
    int b = blockIdx.x, seg = 0;
    #pragma unroll
    for (int s = 0; s < 6; ++s) if (b >= a.blkoff[s + 1]) seg = s + 1;
    int i = (b - a.blkoff[seg]) * 256 + threadIdx.x;
    if (i * 4 >= a.n[seg]) return;
    if (a.F[a.fidx[seg]]) {
        float4 f = reinterpret_cast<const float4*>(a.src[seg])[i];
        ushort4 o;
        o.x = f2b(f.x); o.y = f2b(f.y); o.z = f2b(f.z); o.w = f2b(f.w);
        reinterpret_cast<ushort4*>(a.dst[seg])[i] = o;
    } else {
        reinterpret_cast<ushort4*>(a.dst[seg])[i] =
            reinterpret_cast<const ushort4*>(a.src[seg])[i];
    }
}

// ---------------- split-K reduce: out = P0 + P1 + resid (fp32 out) --------
__global__ __launch_bounds__(256) void reduce2_kernel(
        const float* __restrict__ P, const unsigned short* __restrict__ resid,
        float* __restrict__ out, int n4) {
    int i = blockIdx.x * 256 + threadIdx.x;
    if (i >= n4) return;
    float4 a = reinterpret_cast<const float4*>(P)[i];
    float4 b = reinterpret_cast<const float4*>(P + (size_t)MROWS * EMB)[i];
    ushort4 r = reinterpret_cast<const ushort4*>(resid)[i];
    float4 o;
    o.x = a.x + b.x + b2f(r.x);
    o.y = a.y + b.y + b2f(r.y);
    o.z = a.z + b.z + b2f(r.z);
    o.w = a.w + b.w + b2f(r.w);
    reinterpret_cast<float4*>(out)[i] = o;
}

// ---------------- LayerNorm: one wave per row; bf16 out -------------------
__global__ __launch_bounds__(256) void ln_kernel(
        const void* __restrict__ x,     const int* __restrict__ fx,
        const void* __restrict__ scale, const int* __restrict__ fsc,
        const void* __restrict__ shift, const int* __restrict__ fsh,
        unsigned short* __restrict__ out) {
    const bool xf = fx && *fx, scf = fsc && *fsc, shf = fsh && *fsh;
    int wave = threadIdx.x >> 6;
    int lane = threadIdx.x & 63;
    int row  = blockIdx.x * 4 + wave;
    const size_t rbase = (size_t)row * EMB;
    float v[12];
    float s = 0.f, s2 = 0.f;
    #pragma unroll
    for (int i = 0; i < 3; ++i) {
        float4 a = load4f(x, rbase + i * 256 + lane * 4, xf);
        v[i*4+0] = a.x; v[i*4+1] = a.y; v[i*4+2] = a.z; v[i*4+3] = a.w;
        s  += a.x + a.y + a.z + a.w;
        s2 += a.x*a.x + a.y*a.y + a.z*a.z + a.w*a.w;
    }
    #pragma unroll
    for (int off = 1; off < 64; off <<= 1) {
        s  += __shfl_xor(s,  off);
        s2 += __shfl_xor(s2, off);
    }
    float mean = s * (1.f / EMB);
    float var  = fmaxf(s2 * (1.f / EMB) - mean * mean, 0.f);
    float rstd = rsqrtf(var + 1e-5f);
    unsigned short* orow = out + rbase;
    #pragma unroll
    for (int i = 0; i < 3; ++i) {
        float4 sc = load4f(scale, i * 256 + lane * 4, scf);
        float4 sh = load4f(shift, i * 256 + lane * 4, shf);
        ushort4 o;
        o.x = f2b((v[i*4+0] - mean) * rstd * sc.x + sh.x);
        o.y = f2b((v[i*4+1] - mean) * rstd * sc.y + sh.y);
        o.z = f2b((v[i*4+2] - mean) * rstd * sc.z + sh.z);
        o.w = f2b((v[i*4+3] - mean) * rstd * sc.w + sh.w);
        *reinterpret_cast<ushort4*>(orow + i * 256 + lane * 4) = o;
    }
}

// ---------------- gemm_lds: bf16 GEMM, dbuf async LDS, XOR-swizzled -------
// v4: + launch_bounds(256,4) (VGPR 56, LDS 32KB -> 4-5 blocks/CU feasible;
// occupancy was the residual limiter at 2.4 blocks avg) and T1 XCD-chunked
// block swizzle (all our grids are %8==0; consecutive dispatch blocks share
// the full W-panel, chunking makes panel re-reads L2-local; m192 +10% when
// HBM/latency-bound). Structure otherwise unchanged (dbuf, one barrier/K-step,
// XOR-swizzled LDS, conflict-free verified by r3 PMC).
template<bool GELU, bool RESID, bool OUTF32>
__global__ __launch_bounds__(256, 4) void gemm_lds(
        const unsigned short* __restrict__ A,
        const unsigned short* __restrict__ W,
        const void* R, const int* __restrict__ fR, size_t rOff,
        void* C, int M, int N, int K, int lda, int ldw) {
    constexpr int BK = 32;
    __shared__ __align__(16) unsigned short sA[2][128 * BK];
    __shared__ __align__(16) unsigned short sB[2][128 * BK];
    // T1: XCD-chunked remap of the linear (x-fastest) dispatch index.
    const int gx = gridDim.x;
    int lin = blockIdx.y * gx + blockIdx.x;
    {
        const int nwg = gx * gridDim.y;
        if ((nwg & 7) == 0) {
            const int cpx = nwg >> 3;
            lin = (lin & 7) * cpx + (lin >> 3);
        }
    }
    const int m0 = (lin % gx) * 128, n0 = (lin / gx) * 128;
    const int kz = blockIdx.z;
    const int t = threadIdx.x, wave = t >> 6;
    const int lane = t & 63;
    const int wrow = (wave >> 1) * 64, wcol = (wave & 1) * 64;
    const int quad = lane >> 4, lr = lane & 15;
    const int r0 = t >> 2;                          // staging row 0..63
    const int scg = (t & 3) ^ ((t >> 3) & 3);       // swizzled col-group
    const int c0 = scg * 8;
    const int xq = quad ^ ((lr >> 1) & 3);          // read-side xor (lane-const)
    const bool rf = fR && *fR;

    A += (size_t)kz * K;
    W += (size_t)kz * K;

    f32x4 acc[4][4];
    #pragma unroll
    for (int i = 0; i < 4; ++i)
        #pragma unroll
        for (int j = 0; j < 4; ++j)
            acc[i][j] = (f32x4){0.f, 0.f, 0.f, 0.f};

    const unsigned short* gA0 = A + (size_t)(m0 + r0) * lda + c0;
    const unsigned short* gA1 = A + (size_t)(m0 + 64 + r0) * lda + c0;
    const unsigned short* gB0 = W + (size_t)(n0 + r0) * ldw + c0;
    const unsigned short* gB1 = W + (size_t)(n0 + 64 + r0) * ldw + c0;

    // prologue: stage tile 0 into buffer 0
#if HAS_GLL
    gll16(gA0, sA[0] + wave * 512);
    gll16(gA1, sA[0] + 2048 + wave * 512);
    gll16(gB0, sB[0] + wave * 512);
    gll16(gB1, sB[0] + 2048 + wave * 512);
#else
    *reinterpret_cast<int4*>(sA[0] + t * 8)        = *reinterpret_cast<const int4*>(gA0);
    *reinterpret_cast<int4*>(sA[0] + 2048 + t * 8) = *reinterpret_cast<const int4*>(gA1);
    *reinterpret_cast<int4*>(sB[0] + t * 8)        = *reinterpret_cast<const int4*>(gB0);
    *reinterpret_cast<int4*>(sB[0] + 2048 + t * 8) = *reinterpret_cast<const int4*>(gB1);
#endif
    __syncthreads();

    int buf = 0;
    for (int k0 = 0; k0 < K; k0 += BK) {
        // prefetch next K-tile into the other buffer (before compute)
        if (k0 + BK < K) {
            const int pf = buf ^ 1;
            const int kn = k0 + BK;
#if HAS_GLL
            gll16(gA0 + kn, sA[pf] + wave * 512);
            gll16(gA1 + kn, sA[pf] + 2048 + wave * 512);
            gll16(gB0 + kn, sB[pf] + wave * 512);
            gll16(gB1 + kn, sB[pf] + 2048 + wave * 512);
#else
            *reinterpret_cast<int4*>(sA[pf] + t * 8)        = *reinterpret_cast<const int4*>(gA0 + kn);
            *reinterpret_cast<int4*>(sA[pf] + 2048 + t * 8) = *reinterpret_cast<const int4*>(gA1 + kn);
            *reinterpret_cast<int4*>(sB[pf] + t * 8)        = *reinterpret_cast<const int4*>(gB0 + kn);
            *reinterpret_cast<int4*>(sB[pf] + 2048 + t * 8) = *reinterpret_cast<const int4*>(gB1 + kn);
#endif
        }
        // compute current buffer
        bf16x8 af[4], bfv[4];
        #pragma unroll
        for (int i = 0; i < 4; ++i)
            af[i] = *reinterpret_cast<const bf16x8*>(
                sA[buf] + (wrow >> 6) * 2048 + (i * 16 + lr) * 32 + xq * 8);
        #pragma unroll
        for (int j = 0; j < 4; ++j)
            bfv[j] = *reinterpret_cast<const bf16x8*>(
                sB[buf] + (wcol >> 6) * 2048 + (j * 16 + lr) * 32 + xq * 8);
        #pragma unroll
        for (int i = 0; i < 4; ++i)
            #pragma unroll
            for (int j = 0; j < 4; ++j)
                acc[i][j] = __builtin_amdgcn_mfma_f32_16x16x32_bf16(af[i], bfv[j], acc[i][j], 0, 0, 0);
        // one barrier: (a) all reads of buf done before it's restaged next
        // iter; (b) vmcnt(0) drain completes the prefetch into buf^1
        __syncthreads();
        buf ^= 1;
    }

    float* Cf = (float*)C + (size_t)kz * M * N;
    #pragma unroll
    for (int i = 0; i < 4; ++i) {
        #pragma unroll
        for (int j = 0; j < 4; ++j) {
            #pragma unroll
            for (int r = 0; r < 4; ++r) {
                int row = m0 + wrow + i * 16 + quad * 4 + r;
                int col = n0 + wcol + j * 16 + lr;
                float val = acc[i][j][r];
                if (GELU) val = gelu_f(val);
                size_t idx = (size_t)row * N + col;
                if (RESID) {
                    float rv = rf ? ((const float*)R)[idx + rOff]
                                  : b2f(((const unsigned short*)R)[idx + rOff]);
                    val += rv;
                }
                if (OUTF32) Cf[idx] = val;
                else {
                    bf16_t hv = (bf16_t)val;
                    ((unsigned short*)C)[idx] = *reinterpret_cast<unsigned short*>(&hv);
                }
            }
        }
    }
}

// ---------------- legacy flagged GEMM (fallback tiers only) ---------------
template<bool GELU, bool RESID, bool OUTF32>
__global__ __launch_bounds__(256) void gemm_bt(
        const unsigned short* __restrict__ A,
        const void* __restrict__ W, const int* __restrict__ fW,
        const void* R, const int* __restrict__ fR, size_t rOff,
        void* C,
        int M, int N, int K) {
    const bool wf = fW && *fW;
    const bool rf = fR && *fR;
    constexpr int BK = 32, PAD = 8, LDW = BK + PAD;
    __shared__ __align__(16) unsigned short sA[128 * LDW];
    __shared__ __align__(16) unsigned short sB[128 * LDW];
    const int m0 = blockIdx.x * 128;
    const int n0 = blockIdx.y * 128;
    const int t    = threadIdx.x;
    const int wave = t >> 6, lane = t & 63;
    const int wrow = (wave >> 1) * 64, wcol = (wave & 1) * 64;
    const int quad = lane >> 4, lr = lane & 15;
    const int srow = t >> 2, scol = (t & 3) * 8;

    f32x4 acc[4][4];
    #pragma unroll
    for (int i = 0; i < 4; ++i)
        #pragma unroll
        for (int j = 0; j < 4; ++j)
            acc[i][j] = (f32x4){0.f, 0.f, 0.f, 0.f};

    const size_t aBase = (size_t)(m0 + srow) * K + scol;
    const size_t bBase = (size_t)(n0 + srow) * K + scol;

    for (int k0 = 0; k0 < K; k0 += BK) {
        int4 av0 = *reinterpret_cast<const int4*>(A + aBase + k0);
        int4 av1 = *reinterpret_cast<const int4*>(A + aBase + (size_t)64 * K + k0);
        int4 bv0 = load8(W, bBase + k0, wf);
        int4 bv1 = load8(W, bBase + (size_t)64 * K + k0, wf);
        *reinterpret_cast<int4*>(sA + srow * LDW + scol)        = av0;
        *reinterpret_cast<int4*>(sA + (srow + 64) * LDW + scol) = av1;
        *reinterpret_cast<int4*>(sB + srow * LDW + scol)        = bv0;
        *reinterpret_cast<int4*>(sB + (srow + 64) * LDW + scol) = bv1;
        __syncthreads();
        bf16x8 af[4], bfv[4];
        #pragma unroll
        for (int i = 0; i < 4; ++i)
            af[i] = *reinterpret_cast<const bf16x8*>(sA + (wrow + i * 16 + lr) * LDW + quad * 8);
        #pragma unroll
        for (int j = 0; j < 4; ++j)
            bfv[j] = *reinterpret_cast<const bf16x8*>(sB + (wcol + j * 16 + lr) * LDW + quad * 8);
        #pragma unroll
        for (int i = 0; i < 4; ++i)
            #pragma unroll
            for (int j = 0; j < 4; ++j)
                acc[i][j] = __builtin_amdgcn_mfma_f32_16x16x32_bf16(af[i], bfv[j], acc[i][j], 0, 0, 0);
        __syncthreads();
    }

    #pragma unroll
    for (int i = 0; i < 4; ++i) {
        #pragma unroll
        for (int j = 0; j < 4; ++j) {
            #pragma unroll
            for (int r = 0; r < 4; ++r) {
                int row = m0 + wrow + i * 16 + quad * 4 + r;
                int col = n0 + wcol + j * 16 + lr;
                float val = acc[i][j][r];
                if (GELU) val = gelu_f(val);
                size_t idx = (size_t)row * N + col;
                if (RESID) {
                    float rv = rf ? ((const float*)R)[idx + rOff]
                                  : b2f(((const unsigned short*)R)[idx + rOff]);
                    val += rv;
                }
                if (OUTF32) ((float*)C)[idx] = val;
                else        ((unsigned short*)C)[idx] = f2b(val);
            }
        }
    }
}

// ---------------- MFMA flash attention, paired 64-q tiles ------------------
// v2 (validated r2): K staged via global_load_lds w/ pre-swizzled source,
// Vt transpose-scatter XOR-swizzled, per-wave P buffer swizzled, K/Vt
// double-buffered with one barrier per kt tile, softmax in exp2 space.
__global__ __launch_bounds__(256) void fattn_kernel(
        const unsigned short* __restrict__ q,
        const unsigned short* __restrict__ k,
        const unsigned short* __restrict__ v,
        int rs, unsigned short* __restrict__ ctx) {
    constexpr int VTP = 72;
    __shared__ __align__(16) unsigned short sK[2][64 * 64];
    __shared__ __align__(16) unsigned short Vt[2][64 * VTP];
    __shared__ __align__(16) unsigned short Pl[4][16 * VTP];
    const int tid  = threadIdx.x;
    const int wave = tid >> 6, lane = tid & 63;
    const int quad = lane >> 4, lr = lane & 15;
    const int NH   = gridDim.x >> 3;
    const int head = blockIdx.x % NH;
    const int pr   = blockIdx.x / NH;
    const int bb   = head / NHEADS, hd = head % NHEADS;
    const size_t seqbase = (size_t)bb * SEQ;
    constexpr float C2 = 0.18033688011112042f;   // 0.125 * log2(e)

    const int krow0 = tid >> 3;                           // 0..31 (+32 on pass 1)
    const int dreal = ((tid & 7) * 8) ^ ((krow0 & 7) << 3);
    const int vrow = tid >> 2;                            // 0..63 (k index)
    const int vcol = (tid & 3) * 16;                      // d base
    const int vxr  = vrow ^ ((tid & 3) << 4);             // k ^ ((d>>4)&3)<<4
    const int kswz = (lr & 7) << 3;                       // K read xor
    const int pswr = ((lr >> 2) & 3) << 3;                // P read xor
    unsigned short* Pw = Pl[wave];

    #pragma unroll
    for (int seg = 0; seg < 2; ++seg) {
        const int qt = seg == 0 ? (15 - pr) : pr;
        const int q0 = qt * 64 + wave * 16;

        bf16x8 aQ0, aQ1;
        {
            const unsigned short* qp = q + (seqbase + q0 + lr) * rs + hd * HDIM + quad * 8;
            aQ0 = *reinterpret_cast<const bf16x8*>(qp);
            aQ1 = *reinterpret_cast<const bf16x8*>(qp + 32);
        }

        f32x4 O[4];
        #pragma unroll
        for (int i = 0; i < 4; ++i) O[i] = (f32x4){0.f, 0.f, 0.f, 0.f};
        float mrow[4], lrow[4];
        #pragma unroll
        for (int r = 0; r < 4; ++r) { mrow[r] = -__builtin_inff(); lrow[r] = 0.f; }

        // ---- prologue: stage tile 0 into buffer 0 ----
        {
            const unsigned short* kp = k + (seqbase + krow0) * rs + hd * HDIM + dreal;
            stage16(kp,                   &sK[0][wave * 512],        lane);
            stage16(kp + (size_t)32 * rs, &sK[0][2048 + wave * 512], lane);
            const unsigned short* vp = v + (seqbase + vrow) * rs + hd * HDIM + vcol;
            union { int4 v4; unsigned short u[8]; } pa, pb;
            pa.v4 = *reinterpret_cast<const int4*>(vp);
            pb.v4 = *reinterpret_cast<const int4*>(vp + 8);
            #pragma unroll
            for (int e = 0; e < 8; ++e) Vt[0][(vcol + e) * VTP + vxr]     = pa.u[e];
            #pragma unroll
            for (int e = 0; e < 8; ++e) Vt[0][(vcol + 8 + e) * VTP + vxr] = pb.u[e];
        }
        __syncthreads();

        for (int kt = 0; kt <= qt; ++kt) {
            const int b = kt & 1;
            union { int4 v4; unsigned short u[8]; } ua, ub;
            if (kt < qt) {
                const unsigned short* kp = k + (seqbase + (size_t)(kt + 1) * 64 + krow0) * rs
                                         + hd * HDIM + dreal;
                stage16(kp,                   &sK[b ^ 1][wave * 512],        lane);
                stage16(kp + (size_t)32 * rs, &sK[b ^ 1][2048 + wave * 512], lane);
                const unsigned short* vp = v + (seqbase + (size_t)(kt + 1) * 64 + vrow) * rs
                                         + hd * HDIM + vcol;
                ua.v4 = *reinterpret_cast<const int4*>(vp);
                ub.v4 = *reinterpret_cast<const int4*>(vp + 8);
            }

            f32x4 S[4];
            #pragma unroll
            for (int sub = 0; sub < 4; ++sub) {
                const unsigned short* kr = &sK[b][(sub * 16 + lr) * 64];
                bf16x8 b0 = *reinterpret_cast<const bf16x8*>(kr + ((quad * 8) ^ kswz));
                bf16x8 b1 = *reinterpret_cast<const bf16x8*>(kr + ((32 + quad * 8) ^ kswz));
                f32x4 accS = (f32x4){0.f, 0.f, 0.f, 0.f};
                accS = __builtin_amdgcn_mfma_f32_16x16x32_bf16(aQ0, b0, accS, 0, 0, 0);
                accS = __builtin_amdgcn_mfma_f32_16x16x32_bf16(aQ1, b1, accS, 0, 0, 0);
                S[sub] = accS;
            }
            const bool diag = (kt == qt);
            #pragma unroll
            for (int sub = 0; sub < 4; ++sub) {
                const int kg = kt * 64 + sub * 16 + lr;
                #pragma unroll
                for (int r = 0; r < 4; ++r) {
                    float s = S[sub][r] * C2;
                    if (diag && kg > q0 + quad * 4 + r) s = -__builtin_inff();
                    S[sub][r] = s;
                }
            }
            float mnew[4], alpha[4];
            #pragma unroll
            for (int r = 0; r < 4; ++r) {
                float mx = fmaxf(fmaxf(S[0][r], S[1][r]), fmaxf(S[2][r], S[3][r]));
                #pragma unroll
                for (int m = 1; m < 16; m <<= 1) mx = fmaxf(mx, __shfl_xor(mx, m));
                mnew[r]  = fmaxf(mrow[r], mx);
                alpha[r] = fexp2(mrow[r] - mnew[r]);
                mrow[r]  = mnew[r];
            }
            float rsum[4] = {0.f, 0.f, 0.f, 0.f};
            #pragma unroll
            for (int sub = 0; sub < 4; ++sub)
                #pragma unroll
                for (int r = 0; r < 4; ++r) {
                    float p = fexp2(S[sub][r] - mnew[r]);
                    S[sub][r] = p;
                    rsum[r] += p;
                }
            #pragma unroll
            for (int r = 0; r < 4; ++r) {
                float rs2 = rsum[r];
                #pragma unroll
                for (int m = 1; m < 16; m <<= 1) rs2 += __shfl_xor(rs2, m);
                lrow[r] = lrow[r] * alpha[r] + rs2;
            }

            #pragma unroll
            for (int sub = 0; sub < 4; ++sub)
                #pragma unroll
                for (int r = 0; r < 4; ++r) {
                    bf16_t hv = (bf16_t)S[sub][r];
                    Pw[(quad * 4 + r) * VTP + ((sub * 16 + lr) ^ (quad << 3))] =
                        *reinterpret_cast<unsigned short*>(&hv);
                }
            if (kt < qt) {
                #pragma unroll
                for (int e = 0; e < 8; ++e) Vt[b ^ 1][(vcol + e) * VTP + vxr]     = ua.u[e];
                #pragma unroll
                for (int e = 0; e < 8; ++e) Vt[b ^ 1][(vcol + 8 + e) * VTP + vxr] = ub.u[e];
            }
            #pragma unroll
            for (int d = 0; d < 4; ++d)
                #pragma unroll
                for (int r = 0; r < 4; ++r)
                    O[d][r] *= alpha[r];

            #pragma unroll
            for (int c = 0; c < 2; ++c) {
                bf16x8 aP = *reinterpret_cast<const bf16x8*>(
                    &Pw[lr * VTP + ((c * 32 + quad * 8) ^ pswr)]);
                #pragma unroll
                for (int d = 0; d < 4; ++d) {
                    bf16x8 bV = *reinterpret_cast<const bf16x8*>(
                        &Vt[b][(d * 16 + lr) * VTP + ((c * 32 + quad * 8) ^ (d << 4))]);
                    O[d] = __builtin_amdgcn_mfma_f32_16x16x32_bf16(aP, bV, O[d], 0, 0, 0);
                }
            }
            __syncthreads();
        }

        #pragma unroll
        for (int r = 0; r < 4; ++r) {
            const float rinv = 1.f / lrow[r];
            const int qg = q0 + quad * 4 + r;
            unsigned short* crow = ctx + (seqbase + qg) * EMB + hd * HDIM;
            #pragma unroll
            for (int d = 0; d < 4; ++d)
                crow[d * 16 + lr] = f2b(O[d][r] * rinv);
        }
    }
}

// ---------------------------------------------------------------------------
extern "C" void kernel_launch(void* const* d_in, const int* in_sizes, int n_in,
                              void* d_out, int out_size, void* d_ws, size_t ws_size,
                              hipStream_t stream) {
    const void* x  = d_in[0];
    const void* wq = d_in[1], *wk = d_in[2], *wv = d_in[3], *wo = d_in[4];
    const void* w1 = d_in[5], *w2 = d_in[6];
    const void* g1 = d_in[7], *s1 = d_in[8], *g2 = d_in[9], *s2 = d_in[10];
    char* ws = (char*)d_ws;
    dim3 blk(256);

    int* F = (int*)ws;
    {
        DetectArgs da;
        for (int i = 0; i < 11; ++i) { da.p[i] = (const unsigned short*)d_in[i]; da.n[i] = in_sizes[i]; }
        detect_all<<<11, blk, 0, stream>>>(da, F);
    }

    const size_t SZE = (size_t)MROWS * EMB;
    const size_t SZB = SZE * 2;
    unsigned short* base = (unsigned short*)(ws + 256);
    dim3 g768(MROWS / 128, EMB / 128);

    const size_t FULLB = 256 + 2ULL * (2 * W4E) + 2ULL * (4 * W2E)
                       + 2ULL * ((size_t)MROWS * 2304) + 2 * SZB
                       + 2ULL * ((size_t)MROWS * FFN);   // = 127,402,240 B
    const size_t FULLB2 = FULLB + 2ULL * SZE * 4;        // + 50.3 MB fp32 partials

    if (ws_size >= FULLB2) {
        // ---- full path + split-K FFN2 ----
        unsigned short* w1b   = base;
        unsigned short* w2b   = w1b + W4E;
        unsigned short* wqkvb = w2b + W4E;
        unsigned short* wob   = wqkvb + 3 * W2E;
        unsigned short* P     = wob + W2E;
        unsigned short* B0    = P + (size_t)MROWS * 2304;
        unsigned short* B1    = B0 + SZE;
        unsigned short* G     = B1 + SZE;
        float*          PK    = (float*)(G + (size_t)MROWS * FFN);

        {
            CvtArgs ca;
            ca.src[0] = wq; ca.src[1] = wk; ca.src[2] = wv;
            ca.src[3] = wo; ca.src[4] = w1; ca.src[5] = w2;
            ca.dst[0] = wqkvb; ca.dst[1] = wqkvb + W2E; ca.dst[2] = wqkvb + 2 * W2E;
            ca.dst[3] = wob;   ca.dst[4] = w1b;         ca.dst[5] = w2b;
            ca.n[0] = ca.n[1] = ca.n[2] = ca.n[3] = W2E; ca.n[4] = ca.n[5] = W4E;
            int off = 0;
            for (int s = 0; s < 6; ++s) { ca.blkoff[s] = off; off += ca.n[s] / 1024; }
            ca.blkoff[6] = off;
            ca.F = F;
            ca.fidx[0] = 1; ca.fidx[1] = 2; ca.fidx[2] = 3;
            ca.fidx[3] = 4; ca.fidx[4] = 5; ca.fidx[5] = 6;
            cvt_weights<<<off, blk, 0, stream>>>(ca);
        }

        ln_kernel<<<MROWS / 4, blk, 0, stream>>>(x, F+0, g1, F+7, s1, F+8, B1);
        dim3 gqkv(MROWS / 128, 2304 / 128);
        gemm_lds<false, false, false><<<gqkv, blk, 0, stream>>>(B1, wqkvb, nullptr, nullptr, 0, P, MROWS, 2304, EMB, EMB, EMB);
        fattn_kernel<<<BATCH * NHEADS * 8, blk, 0, stream>>>(P, P + 768, P + 1536, 2304, B0);
        gemm_lds<false, true, false><<<g768, blk, 0, stream>>>(B0, wob, x, F+0, 0, B1, MROWS, EMB, EMB, EMB, EMB);
        ln_kernel<<<MROWS / 4, blk, 0, stream>>>(B1, nullptr, g2, F+9, s2, F+10, B0);
        dim3 gffn1(MROWS / 128, FFN / 128);
        gemm_lds<true, false, false><<<gffn1, blk, 0, stream>>>(B0, w1b, nullptr, nullptr, 0, G, MROWS, FFN, EMB, EMB, EMB);
        dim3 gsk(MROWS / 128, EMB / 128, 2);
        gemm_lds<false, false, true><<<gsk, blk, 0, stream>>>(G, w2b, nullptr, nullptr, 0, PK, MROWS, EMB, FFN / 2, FFN, FFN);
        reduce2_kernel<<<(SZE / 4 + 255) / 256, blk, 0, stream>>>(PK, B1, (float*)d_out, SZE / 4);
    } else if (ws_size >= FULLB) {
        // ---- full path, single-launch FFN2 ----
        unsigned short* w1b   = base;
        unsigned short* w2b   = w1b + W4E;
        unsigned short* wqkvb = w2b + W4E;
        unsigned short* wob   = wqkvb + 3 * W2E;
        unsigned short* P     = wob + W2E;
        unsigned short* B0    = P + (size_t)MROWS * 2304;
        unsigned short* B1    = B0 + SZE;
        unsigned short* G     = B1 + SZE;

        {
            CvtArgs ca;
            ca.src[0] = wq; ca.src[1] = wk; ca.src[2] = wv;
            ca.src[3] = wo; ca.src[4] = w1; ca.src[5] = w2;
            ca.dst[0] = wqkvb; ca.dst[1] = wqkvb + W2E; ca.dst[2] = wqkvb + 2 * W2E;
            ca.dst[3] = wob;   ca.dst[4] = w1b;         ca.dst[5] = w2b;
            ca.n[0] = ca.n[1] = ca.n[2] = ca.n[3] = W2E; ca.n[4] = ca.n[5] = W4E;
            int off = 0;
            for (int s = 0; s < 6; ++s) { ca.blkoff[s] = off; off += ca.n[s] / 1024; }
            ca.blkoff[6] = off;
            ca.F = F;
            ca.fidx[0] = 1; ca.fidx[1] = 2; ca.fidx[2] = 3;
            ca.fidx[3] = 4; ca.fidx[4] = 5; ca.fidx[5] = 6;
            cvt_weights<<<off, blk, 0, stream>>>(ca);
        }

        ln_kernel<<<MROWS / 4, blk, 0, stream>>>(x, F+0, g1, F+7, s1, F+8, B1);
        dim3 gqkv(MROWS / 128, 2304 / 128);
        gemm_lds<false, false, false><<<gqkv, blk, 0, stream>>>(B1, wqkvb, nullptr, nullptr, 0, P, MROWS, 2304, EMB, EMB, EMB);
        fattn_kernel<<<BATCH * NHEADS * 8, blk, 0, stream>>>(P, P + 768, P + 1536, 2304, B0);
        gemm_lds<false, true, false><<<g768, blk, 0, stream>>>(B0, wob, x, F+0, 0, B1, MROWS, EMB, EMB, EMB, EMB);
        ln_kernel<<<MROWS / 4, blk, 0, stream>>>(B1, nullptr, g2, F+9, s2, F+10, B0);
        dim3 gffn1(MROWS / 128, FFN / 128);
        gemm_lds<true, false, false><<<gffn1, blk, 0, stream>>>(B0, w1b, nullptr, nullptr, 0, G, MROWS, FFN, EMB, EMB, EMB);
        gemm_lds<false, true, true><<<g768, blk, 0, stream>>>(G, w2b, B1, nullptr, 0, d_out, MROWS, EMB, FFN, FFN, FFN);
    } else if (ws_size >= 256 + 4 * SZB) {
        // ---- fallback tier M ----
        unsigned short* B0 = base;
        unsigned short* B1 = B0 + SZE;
        unsigned short* B2 = B1 + SZE;
        unsigned short* B3 = B2 + SZE;
        ln_kernel<<<MROWS / 4, blk, 0, stream>>>(x, F+0, g1, F+7, s1, F+8, B0);
        gemm_bt<false, false, false><<<g768, blk, 0, stream>>>(B0, wq, F+1, nullptr, nullptr, 0, B1, MROWS, EMB, EMB);
        gemm_bt<false, false, false><<<g768, blk, 0, stream>>>(B0, wk, F+2, nullptr, nullptr, 0, B2, MROWS, EMB, EMB);
        gemm_bt<false, false, false><<<g768, blk, 0, stream>>>(B0, wv, F+3, nullptr, nullptr, 0, B3, MROWS, EMB, EMB);
        fattn_kernel<<<BATCH * NHEADS * 8, blk, 0, stream>>>(B1, B2, B3, EMB, B0);
        gemm_bt<false, true, false><<<g768, blk, 0, stream>>>(B0, wo, F+4, x, F+0, 0, B1, MROWS, EMB, EMB);
        ln_kernel<<<MROWS / 4, blk, 0, stream>>>(B1, nullptr, g2, F+9, s2, F+10, B2);
        dim3 c3072(2048 / 128, FFN / 128), c768(2048 / 128, EMB / 128);
        for (int c = 0; c < 4; ++c) {
            const size_t r0 = (size_t)c * 2048;
            gemm_bt<true, false, false><<<c3072, blk, 0, stream>>>(B2 + r0 * EMB, w1, F+5, nullptr, nullptr, 0, B3, 2048, FFN, EMB);
            gemm_bt<false, true, true><<<c768, blk, 0, stream>>>(B3, w2, F+6, B1 + r0 * EMB, nullptr, 0, (float*)d_out + r0 * EMB, 2048, EMB, FFN);
        }
    } else {
        // ---- fallback tier B ----
        unsigned short* hlow = (unsigned short*)d_out;
        unsigned short* x2up = (unsigned short*)d_out + SZE;
        unsigned short* wsQ = base;
        unsigned short* wsK = wsQ + (size_t)1024 * EMB;
        unsigned short* wsV = wsK + (size_t)1024 * EMB;
        unsigned short* wsC = wsV + (size_t)1024 * EMB;
        ln_kernel<<<MROWS / 4, blk, 0, stream>>>(x, F+0, g1, F+7, s1, F+8, hlow);
        dim3 q768(1024 / 128, EMB / 128);
        for (int grp = 0; grp < BATCH; ++grp) {
            const size_t r0 = (size_t)grp * 1024;
            gemm_bt<false, false, false><<<q768, blk, 0, stream>>>(hlow + r0 * EMB, wq, F+1, nullptr, nullptr, 0, wsQ, 1024, EMB, EMB);
            gemm_bt<false, false, false><<<q768, blk, 0, stream>>>(hlow + r0 * EMB, wk, F+2, nullptr, nullptr, 0, wsK, 1024, EMB, EMB);
            gemm_bt<false, false, false><<<q768, blk, 0, stream>>>(hlow + r0 * EMB, wv, F+3, nullptr, nullptr, 0, wsV, 1024, EMB, EMB);
            fattn_kernel<<<1 * NHEADS * 8, blk, 0, stream>>>(wsQ, wsK, wsV, EMB, wsC);
            gemm_bt<false, true, false><<<q768, blk, 0, stream>>>(wsC, wo, F+4, x, F+0, r0 * EMB, x2up + r0 * EMB, 1024, EMB, EMB);
        }
        unsigned short* xb = base;
        unsigned short* h2 = xb + (size_t)1024 * EMB;
        unsigned short* gb = h2 + (size_t)1024 * EMB;
        dim3 f3072(1024 / 128, FFN / 128), f768(1024 / 128, EMB / 128);
        for (int c = 0; c < BATCH; ++c) {
            const size_t r0 = (size_t)c * 1024;
            hipMemcpyAsync(xb, x2up + r0 * EMB, (size_t)1024 * EMB * 2,
                           hipMemcpyDeviceToDevice, stream);
            ln_kernel<<<1024 / 4, blk, 0, stream>>>(xb, nullptr, g2, F+9, s2, F+10, h2);
            gemm_bt<true, false, false><<<f3072, blk, 0, stream>>>(h2, w1, F+5, nullptr, nullptr, 0, gb, 1024, FFN, EMB);
            gemm_bt<false, true, true><<<f768, blk, 0, stream>>>(gb, w2, F+6, xb, nullptr, 0, (float*)d_out + r0 * EMB, 1024, EMB, FFN);
        }
    }
}

// Round 6
// 379.120 us; speedup vs baseline: 1.0667x; 1.0667x over previous
//
#include <hip/hip_runtime.h>
#include <hip/hip_bf16.h>
#include <cstdint>

#define EMB    768
#define NHEADS 12
#define HDIM   64
#define SEQ    1024
#define BATCH  8
#define MROWS  (BATCH*SEQ)   /* 8192 */
#define FFN    3072
#define W2E    (EMB*EMB)     /* 589824 */
#define W4E    (FFN*EMB)     /* 2359296 */

typedef __bf16 bf16_t;
typedef bf16_t bf16x8 __attribute__((ext_vector_type(8)));
typedef float  f32x4  __attribute__((ext_vector_type(4)));

__device__ __forceinline__ float b2f(unsigned short u) {
    union { unsigned int i; float f; } t; t.i = ((unsigned int)u) << 16; return t.f;
}
__device__ __forceinline__ unsigned short f2b(float f) {
    union { float f; unsigned int i; } t; t.f = f;
    unsigned int lsb = (t.i >> 16) & 1u;
    t.i += 0x7fffu + lsb;
    return (unsigned short)(t.i >> 16);
}
// raw v_exp_f32 (exp2)
__device__ __forceinline__ float fexp2(float x) {
#if defined(__has_builtin)
#if __has_builtin(__builtin_amdgcn_exp2f)
    return __builtin_amdgcn_exp2f(x);
#else
    return exp2f(x);
#endif
#else
    return exp2f(x);
#endif
}
__device__ __forceinline__ float frcp(float x) {
#if defined(__has_builtin)
#if __has_builtin(__builtin_amdgcn_rcpf)
    return __builtin_amdgcn_rcpf(x);
#else
    return 1.f / x;
#endif
#else
    return 1.f / x;
#endif
}
// fast tanh-gelu in exp2 space: gelu(x) = x * sigmoid(2c(x + 0.044715x^3))
__device__ __forceinline__ float gelu_f(float x) {
    float x2 = x * x;
    float u  = x * __builtin_fmaf(x2, -0.10294823f, -2.3022082f);
    return x * frcp(1.f + fexp2(u));
}

#if defined(__has_builtin)
#if __has_builtin(__builtin_amdgcn_global_load_lds)
#define HAS_GLL 1
#endif
#endif
#ifndef HAS_GLL
#define HAS_GLL 0
#endif

__device__ __forceinline__ void gll16(const unsigned short* g, unsigned short* lds_wave_base) {
#if HAS_GLL
    __builtin_amdgcn_global_load_lds(
        (const __attribute__((address_space(1))) unsigned int*)g,
        (__attribute__((address_space(3))) unsigned int*)lds_wave_base, 16, 0, 0);
#endif
}
// staging helper: async global->LDS when available, manual 16B copy otherwise
__device__ __forceinline__ void stage16(const unsigned short* g, unsigned short* lds_wave_base, int lane) {
#if HAS_GLL
    __builtin_amdgcn_global_load_lds(
        (const __attribute__((address_space(1))) unsigned int*)g,
        (__attribute__((address_space(3))) unsigned int*)lds_wave_base, 16, 0, 0);
#else
    *reinterpret_cast<int4*>(lds_wave_base + lane * 8) = *reinterpret_cast<const int4*>(g);
#endif
}

__device__ __forceinline__ int4 load8(const void* src, size_t eoff, bool f32) {
    if (f32) {
        const float4* p = reinterpret_cast<const float4*>((const float*)src + eoff);
        float4 a = p[0], b = p[1];
        union { unsigned short u[8]; int4 v; } r;
        r.u[0] = f2b(a.x); r.u[1] = f2b(a.y); r.u[2] = f2b(a.z); r.u[3] = f2b(a.w);
        r.u[4] = f2b(b.x); r.u[5] = f2b(b.y); r.u[6] = f2b(b.z); r.u[7] = f2b(b.w);
        return r.v;
    }
    return *reinterpret_cast<const int4*>((const unsigned short*)src + eoff);
}
__device__ __forceinline__ float4 load4f(const void* src, size_t eoff, bool f32) {
    if (f32) return *reinterpret_cast<const float4*>((const float*)src + eoff);
    ushort4 u = *reinterpret_cast<const ushort4*>((const unsigned short*)src + eoff);
    float4 r; r.x = b2f(u.x); r.y = b2f(u.y); r.z = b2f(u.z); r.w = b2f(u.w);
    return r;
}

// ---------------- dtype probe: one block per input ------------------------
struct DetectArgs { const unsigned short* p[11]; int n[11]; };

__global__ __launch_bounds__(256) void detect_all(DetectArgs a, int* __restrict__ flags) {
    __shared__ int cnt;
    if (threadIdx.x == 0) cnt = 0;
    __syncthreads();
    const unsigned short* src = a.p[blockIdx.x];
    int npairs = a.n[blockIdx.x] / 2;
    if (npairs > 4096) npairs = 4096;
    int local = 0;
    for (int p = threadIdx.x; p < npairs; p += 256) {
        unsigned short u0 = src[2 * p], u1 = src[2 * p + 1];
        int e0 = (u0 >> 7) & 0xFF;
        bool insane0 = (e0 == 0xFF) || (u0 != 0 && (e0 < 96 || e0 > 159));
        bool zpat    = (u0 == 0 && u1 != 0);
        if (insane0 || zpat) ++local;
    }
    atomicAdd(&cnt, local);
    __syncthreads();
    if (threadIdx.x == 0) flags[blockIdx.x] = (cnt * 8 > npairs) ? 1 : 0;
}

// ---------------- adaptive convert (middle tier) --------------------------
__global__ __launch_bounds__(256) void cvt_adapt(
        const void* __restrict__ src, unsigned short* __restrict__ dst,
        int n, const int* __restrict__ flag) {
    int i = blockIdx.x * 256 + threadIdx.x;
    if (i * 4 >= n) return;
    if (*flag) {
        float4 f = reinterpret_cast<const float4*>(src)[i];
        ushort4 o;
        o.x = f2b(f.x); o.y = f2b(f.y); o.z = f2b(f.z); o.w = f2b(f.w);
        reinterpret_cast<ushort4*>(dst)[i] = o;
    } else {
        reinterpret_cast<ushort4*>(dst)[i] = reinterpret_cast<const ushort4*>(src)[i];
    }
}

// ---------------- fused weight convert: all 6 weights, one launch ---------
struct CvtArgs {
    const void* src[6];
    unsigned short* dst[6];
    int n[6];
    int blkoff[7];
    const int* F;
    int fidx[6];
};
__global__ __launch_bounds__(256) void cvt_weights(CvtArgs a) {
    int b = blockIdx.x, seg = 0;
    #pragma unroll
    for (int s = 0; s < 6; ++s) if (b >= a.blkoff[s + 1]) seg = s + 1;
    int i = (b - a.blkoff[seg]) * 256 + threadIdx.x;
    if (i * 4 >= a.n[seg]) return;
    if (a.F[a.fidx[seg]]) {
        float4 f = reinterpret_cast<const float4*>(a.src[seg])[i];
        ushort4 o;
        o.x = f2b(f.x); o.y = f2b(f.y); o.z = f2b(f.z); o.w = f2b(f.w);
        reinterpret_cast<ushort4*>(a.dst[seg])[i] = o;
    } else {
        reinterpret_cast<ushort4*>(a.dst[seg])[i] =
            reinterpret_cast<const ushort4*>(a.src[seg])[i];
    }
}

// ---------------- split-K reduce: out = P0 + P1 + resid (fp32 out) --------
__global__ __launch_bounds__(256) void reduce2_kernel(
        const float* __restrict__ P, const unsigned short* __restrict__ resid,
        float* __restrict__ out, int n4) {
    int i = blockIdx.x * 256 + threadIdx.x;
    if (i >= n4) return;
    float4 a = reinterpret_cast<const float4*>(P)[i];
    float4 b = reinterpret_cast<const float4*>(P + (size_t)MROWS * EMB)[i];
    ushort4 r = reinterpret_cast<const ushort4*>(resid)[i];
    float4 o;
    o.x = a.x + b.x + b2f(r.x);
    o.y = a.y + b.y + b2f(r.y);
    o.z = a.z + b.z + b2f(r.z);
    o.w = a.w + b.w + b2f(r.w);
    reinterpret_cast<float4*>(out)[i] = o;
}

// ---------------- LayerNorm: one wave per row; bf16 out -------------------
__global__ __launch_bounds__(256) void ln_kernel(
        const void* __restrict__ x,     const int* __restrict__ fx,
        const void* __restrict__ scale, const int* __restrict__ fsc,
        const void* __restrict__ shift, const int* __restrict__ fsh,
        unsigned short* __restrict__ out) {
    const bool xf = fx && *fx, scf = fsc && *fsc, shf = fsh && *fsh;
    int wave = threadIdx.x >> 6;
    int lane = threadIdx.x & 63;
    int row  = blockIdx.x * 4 + wave;
    const size_t rbase = (size_t)row * EMB;
    float v[12];
    float s = 0.f, s2 = 0.f;
    #pragma unroll
    for (int i = 0; i < 3; ++i) {
        float4 a = load4f(x, rbase + i * 256 + lane * 4, xf);
        v[i*4+0] = a.x; v[i*4+1] = a.y; v[i*4+2] = a.z; v[i*4+3] = a.w;
        s  += a.x + a.y + a.z + a.w;
        s2 += a.x*a.x + a.y*a.y + a.z*a.z + a.w*a.w;
    }
    #pragma unroll
    for (int off = 1; off < 64; off <<= 1) {
        s  += __shfl_xor(s,  off);
        s2 += __shfl_xor(s2, off);
    }
    float mean = s * (1.f / EMB);
    float var  = fmaxf(s2 * (1.f / EMB) - mean * mean, 0.f);
    float rstd = rsqrtf(var + 1e-5f);
    unsigned short* orow = out + rbase;
    #pragma unroll
    for (int i = 0; i < 3; ++i) {
        float4 sc = load4f(scale, i * 256 + lane * 4, scf);
        float4 sh = load4f(shift, i * 256 + lane * 4, shf);
        ushort4 o;
        o.x = f2b((v[i*4+0] - mean) * rstd * sc.x + sh.x);
        o.y = f2b((v[i*4+1] - mean) * rstd * sc.y + sh.y);
        o.z = f2b((v[i*4+2] - mean) * rstd * sc.z + sh.z);
        o.w = f2b((v[i*4+3] - mean) * rstd * sc.w + sh.w);
        *reinterpret_cast<ushort4*>(orow + i * 256 + lane * 4) = o;
    }
}

// ---------------- gemm_lds: bf16 GEMM, counted-vmcnt triple-buffer --------
// v5: T4 counted vmcnt. 3 LDS buffer sets (48KB), prefetch distance 2, ONE
// raw s_barrier per K-step preceded by s_waitcnt vmcnt(4).
// Soundness (per-segment analysis): segment i = [barrier_{i-1}, barrier_i]
// contains issue(i+2)->buf[(i+2)%3] and compute(i)->buf[i%3] (disjoint);
// buf[(i+2)%3]'s last reads were compute(i-1), sealed by barrier_{i-1};
// RAW: each wave's vmcnt(4) before barrier_{i-1} retires tile i's 4 glls
// (8 outstanding -> <=4), barrier publishes completion to all waves.
// The drain distance becomes ~2 K-steps (~500cy) instead of ~150cy, so the
// gll latency is hidden (m218: counted-vs-drain0 is where the pipeline
// gain lives). XCD swizzle REVERTED (r5: linear chunking put the whole A
// matrix in every XCD's L2 -> FETCH 30->116MB; natural round-robin keeps
// 8 A-panels/XCD resident).
template<bool GELU, bool RESID, bool OUTF32>
__global__ __launch_bounds__(256, 3) void gemm_lds(
        const unsigned short* __restrict__ A,
        const unsigned short* __restrict__ W,
        const void* R, const int* __restrict__ fR, size_t rOff,
        void* C, int M, int N, int K, int lda, int ldw) {
    constexpr int BK = 32;
    __shared__ __align__(16) unsigned short sA[3][128 * BK];
    __shared__ __align__(16) unsigned short sB[3][128 * BK];
    const int m0 = blockIdx.x * 128, n0 = blockIdx.y * 128;
    const int kz = blockIdx.z;
    const int t = threadIdx.x, wave = t >> 6;
    const int lane = t & 63;
    const int wrow = (wave >> 1) * 64, wcol = (wave & 1) * 64;
    const int quad = lane >> 4, lr = lane & 15;
    const int r0 = t >> 2;                          // staging row 0..63
    const int scg = (t & 3) ^ ((t >> 3) & 3);       // swizzled col-group
    const int c0 = scg * 8;
    const int xq = quad ^ ((lr >> 1) & 3);          // read-side xor (lane-const)
    const bool rf = fR && *fR;

    A += (size_t)kz * K;
    W += (size_t)kz * K;

    f32x4 acc[4][4];
    #pragma unroll
    for (int i = 0; i < 4; ++i)
        #pragma unroll
        for (int j = 0; j < 4; ++j)
            acc[i][j] = (f32x4){0.f, 0.f, 0.f, 0.f};

    const unsigned short* gA0 = A + (size_t)(m0 + r0) * lda + c0;
    const unsigned short* gA1 = A + (size_t)(m0 + 64 + r0) * lda + c0;
    const unsigned short* gB0 = W + (size_t)(n0 + r0) * ldw + c0;
    const unsigned short* gB1 = W + (size_t)(n0 + 64 + r0) * ldw + c0;

    const int nk = K / BK;

#if HAS_GLL
    // per-wave: exactly 4 gll instructions per staged tile
    #define STAGE_T(tile, bsel)                                       \
        do {                                                          \
            const int kk_ = (tile) * BK;                              \
            gll16(gA0 + kk_, sA[bsel] + wave * 512);                  \
            gll16(gA1 + kk_, sA[bsel] + 2048 + wave * 512);           \
            gll16(gB0 + kk_, sB[bsel] + wave * 512);                  \
            gll16(gB1 + kk_, sB[bsel] + 2048 + wave * 512);           \
        } while (0)

    // prologue: tiles 0,1 in flight; retire tile 0; publish.
    STAGE_T(0, 0);
    if (nk > 1) {
        STAGE_T(1, 1);
        asm volatile("s_waitcnt vmcnt(4)" ::: "memory");
    } else {
        asm volatile("s_waitcnt vmcnt(0)" ::: "memory");
    }
    __builtin_amdgcn_s_barrier();
    asm volatile("" ::: "memory");

    int cur = 0;
    for (int i = 0; i < nk; ++i) {
        if (i + 2 < nk) {
            int pf = cur + 2; if (pf >= 3) pf -= 3;
            STAGE_T(i + 2, pf);
        }
        bf16x8 af[4], bfv[4];
        #pragma unroll
        for (int ii = 0; ii < 4; ++ii)
            af[ii] = *reinterpret_cast<const bf16x8*>(
                sA[cur] + (wrow >> 6) * 2048 + (ii * 16 + lr) * 32 + xq * 8);
        #pragma unroll
        for (int j = 0; j < 4; ++j)
            bfv[j] = *reinterpret_cast<const bf16x8*>(
                sB[cur] + (wcol >> 6) * 2048 + (j * 16 + lr) * 32 + xq * 8);
        #pragma unroll
        for (int ii = 0; ii < 4; ++ii)
            #pragma unroll
            for (int j = 0; j < 4; ++j)
                acc[ii][j] = __builtin_amdgcn_mfma_f32_16x16x32_bf16(af[ii], bfv[j], acc[ii][j], 0, 0, 0);
        // retire the NEXT tile's loads (counted: newest 4 may stay in flight),
        // then publish. Compiler fence keeps ops on their side of the barrier.
        if (i + 2 < nk) {
            asm volatile("s_waitcnt vmcnt(4)" ::: "memory");
        } else if (i + 1 < nk) {
            asm volatile("s_waitcnt vmcnt(0)" ::: "memory");
        }
        if (i + 1 < nk) {
            __builtin_amdgcn_s_barrier();
            asm volatile("" ::: "memory");
        }
        cur += 1; if (cur == 3) cur = 0;
    }
    #undef STAGE_T
#else
    // fallback: manual stores, 2-buffer, full-drain barriers
    int cur = 0;
    {
        *reinterpret_cast<int4*>(sA[0] + t * 8)        = *reinterpret_cast<const int4*>(gA0);
        *reinterpret_cast<int4*>(sA[0] + 2048 + t * 8) = *reinterpret_cast<const int4*>(gA1);
        *reinterpret_cast<int4*>(sB[0] + t * 8)        = *reinterpret_cast<const int4*>(gB0);
        *reinterpret_cast<int4*>(sB[0] + 2048 + t * 8) = *reinterpret_cast<const int4*>(gB1);
        __syncthreads();
    }
    for (int i = 0; i < nk; ++i) {
        if (i + 1 < nk) {
            int pf = cur ^ 1;
            const int kn = (i + 1) * BK;
            *reinterpret_cast<int4*>(sA[pf] + t * 8)        = *reinterpret_cast<const int4*>(gA0 + kn);
            *reinterpret_cast<int4*>(sA[pf] + 2048 + t * 8) = *reinterpret_cast<const int4*>(gA1 + kn);
            *reinterpret_cast<int4*>(sB[pf] + t * 8)        = *reinterpret_cast<const int4*>(gB0 + kn);
            *reinterpret_cast<int4*>(sB[pf] + 2048 + t * 8) = *reinterpret_cast<const int4*>(gB1 + kn);
        }
        bf16x8 af[4], bfv[4];
        #pragma unroll
        for (int ii = 0; ii < 4; ++ii)
            af[ii] = *reinterpret_cast<const bf16x8*>(
                sA[cur] + (wrow >> 6) * 2048 + (ii * 16 + lr) * 32 + xq * 8);
        #pragma unroll
        for (int j = 0; j < 4; ++j)
            bfv[j] = *reinterpret_cast<const bf16x8*>(
                sB[cur] + (wcol >> 6) * 2048 + (j * 16 + lr) * 32 + xq * 8);
        #pragma unroll
        for (int ii = 0; ii < 4; ++ii)
            #pragma unroll
            for (int j = 0; j < 4; ++j)
                acc[ii][j] = __builtin_amdgcn_mfma_f32_16x16x32_bf16(af[ii], bfv[j], acc[ii][j], 0, 0, 0);
        __syncthreads();
        cur ^= 1;
    }
#endif

    float* Cf = (float*)C + (size_t)kz * M * N;
    #pragma unroll
    for (int i = 0; i < 4; ++i) {
        #pragma unroll
        for (int j = 0; j < 4; ++j) {
            #pragma unroll
            for (int r = 0; r < 4; ++r) {
                int row = m0 + wrow + i * 16 + quad * 4 + r;
                int col = n0 + wcol + j * 16 + lr;
                float val = acc[i][j][r];
                if (GELU) val = gelu_f(val);
                size_t idx = (size_t)row * N + col;
                if (RESID) {
                    float rv = rf ? ((const float*)R)[idx + rOff]
                                  : b2f(((const unsigned short*)R)[idx + rOff]);
                    val += rv;
                }
                if (OUTF32) Cf[idx] = val;
                else {
                    bf16_t hv = (bf16_t)val;
                    ((unsigned short*)C)[idx] = *reinterpret_cast<unsigned short*>(&hv);
                }
            }
        }
    }
}

// ---------------- legacy flagged GEMM (fallback tiers only) ---------------
template<bool GELU, bool RESID, bool OUTF32>
__global__ __launch_bounds__(256) void gemm_bt(
        const unsigned short* __restrict__ A,
        const void* __restrict__ W, const int* __restrict__ fW,
        const void* R, const int* __restrict__ fR, size_t rOff,
        void* C,
        int M, int N, int K) {
    const bool wf = fW && *fW;
    const bool rf = fR && *fR;
    constexpr int BK = 32, PAD = 8, LDW = BK + PAD;
    __shared__ __align__(16) unsigned short sA[128 * LDW];
    __shared__ __align__(16) unsigned short sB[128 * LDW];
    const int m0 = blockIdx.x * 128;
    const int n0 = blockIdx.y * 128;
    const int t    = threadIdx.x;
    const int wave = t >> 6, lane = t & 63;
    const int wrow = (wave >> 1) * 64, wcol = (wave & 1) * 64;
    const int quad = lane >> 4, lr = lane & 15;
    const int srow = t >> 2, scol = (t & 3) * 8;

    f32x4 acc[4][4];
    #pragma unroll
    for (int i = 0; i < 4; ++i)
        #pragma unroll
        for (int j = 0; j < 4; ++j)
            acc[i][j] = (f32x4){0.f, 0.f, 0.f, 0.f};

    const size_t aBase = (size_t)(m0 + srow) * K + scol;
    const size_t bBase = (size_t)(n0 + srow) * K + scol;

    for (int k0 = 0; k0 < K; k0 += BK) {
        int4 av0 = *reinterpret_cast<const int4*>(A + aBase + k0);
        int4 av1 = *reinterpret_cast<const int4*>(A + aBase + (size_t)64 * K + k0);
        int4 bv0 = load8(W, bBase + k0, wf);
        int4 bv1 = load8(W, bBase + (size_t)64 * K + k0, wf);
        *reinterpret_cast<int4*>(sA + srow * LDW + scol)        = av0;
        *reinterpret_cast<int4*>(sA + (srow + 64) * LDW + scol) = av1;
        *reinterpret_cast<int4*>(sB + srow * LDW + scol)        = bv0;
        *reinterpret_cast<int4*>(sB + (srow + 64) * LDW + scol) = bv1;
        __syncthreads();
        bf16x8 af[4], bfv[4];
        #pragma unroll
        for (int i = 0; i < 4; ++i)
            af[i] = *reinterpret_cast<const bf16x8*>(sA + (wrow + i * 16 + lr) * LDW + quad * 8);
        #pragma unroll
        for (int j = 0; j < 4; ++j)
            bfv[j] = *reinterpret_cast<const bf16x8*>(sB + (wcol + j * 16 + lr) * LDW + quad * 8);
        #pragma unroll
        for (int i = 0; i < 4; ++i)
            #pragma unroll
            for (int j = 0; j < 4; ++j)
                acc[i][j] = __builtin_amdgcn_mfma_f32_16x16x32_bf16(af[i], bfv[j], acc[i][j], 0, 0, 0);
        __syncthreads();
    }

    #pragma unroll
    for (int i = 0; i < 4; ++i) {
        #pragma unroll
        for (int j = 0; j < 4; ++j) {
            #pragma unroll
            for (int r = 0; r < 4; ++r) {
                int row = m0 + wrow + i * 16 + quad * 4 + r;
                int col = n0 + wcol + j * 16 + lr;
                float val = acc[i][j][r];
                if (GELU) val = gelu_f(val);
                size_t idx = (size_t)row * N + col;
                if (RESID) {
                    float rv = rf ? ((const float*)R)[idx + rOff]
                                  : b2f(((const unsigned short*)R)[idx + rOff]);
                    val += rv;
                }
                if (OUTF32) ((float*)C)[idx] = val;
                else        ((unsigned short*)C)[idx] = f2b(val);
            }
        }
    }
}

// ---------------- MFMA flash attention, paired 64-q tiles ------------------
// v2 (validated r2): K staged via global_load_lds w/ pre-swizzled source,
// Vt transpose-scatter XOR-swizzled, per-wave P buffer swizzled, K/Vt
// double-buffered with one barrier per kt tile, softmax in exp2 space.
__global__ __launch_bounds__(256) void fattn_kernel(
        const unsigned short* __restrict__ q,
        const unsigned short* __restrict__ k,
        const unsigned short* __restrict__ v,
        int rs, unsigned short* __restrict__ ctx) {
    constexpr int VTP = 72;
    __shared__ __align__(16) unsigned short sK[2][64 * 64];
    __shared__ __align__(16) unsigned short Vt[2][64 * VTP];
    __shared__ __align__(16) unsigned short Pl[4][16 * VTP];
    const int tid  = threadIdx.x;
    const int wave = tid >> 6, lane = tid & 63;
    const int quad = lane >> 4, lr = lane & 15;
    const int NH   = gridDim.x >> 3;
    const int head = blockIdx.x % NH;
    const int pr   = blockIdx.x / NH;
    const int bb   = head / NHEADS, hd = head % NHEADS;
    const size_t seqbase = (size_t)bb * SEQ;
    constexpr float C2 = 0.18033688011112042f;   // 0.125 * log2(e)

    const int krow0 = tid >> 3;                           // 0..31 (+32 on pass 1)
    const int dreal = ((tid & 7) * 8) ^ ((krow0 & 7) << 3);
    const int vrow = tid >> 2;                            // 0..63 (k index)
    const int vcol = (tid & 3) * 16;                      // d base
    const int vxr  = vrow ^ ((tid & 3) << 4);             // k ^ ((d>>4)&3)<<4
    const int kswz = (lr & 7) << 3;                       // K read xor
    const int pswr = ((lr >> 2) & 3) << 3;                // P read xor
    unsigned short* Pw = Pl[wave];

    #pragma unroll
    for (int seg = 0; seg < 2; ++seg) {
        const int qt = seg == 0 ? (15 - pr) : pr;
        const int q0 = qt * 64 + wave * 16;

        bf16x8 aQ0, aQ1;
        {
            const unsigned short* qp = q + (seqbase + q0 + lr) * rs + hd * HDIM + quad * 8;
            aQ0 = *reinterpret_cast<const bf16x8*>(qp);
            aQ1 = *reinterpret_cast<const bf16x8*>(qp + 32);
        }

        f32x4 O[4];
        #pragma unroll
        for (int i = 0; i < 4; ++i) O[i] = (f32x4){0.f, 0.f, 0.f, 0.f};
        float mrow[4], lrow[4];
        #pragma unroll
        for (int r = 0; r < 4; ++r) { mrow[r] = -__builtin_inff(); lrow[r] = 0.f; }

        // ---- prologue: stage tile 0 into buffer 0 ----
        {
            const unsigned short* kp = k + (seqbase + krow0) * rs + hd * HDIM + dreal;
            stage16(kp,                   &sK[0][wave * 512],        lane);
            stage16(kp + (size_t)32 * rs, &sK[0][2048 + wave * 512], lane);
            const unsigned short* vp = v + (seqbase + vrow) * rs + hd * HDIM + vcol;
            union { int4 v4; unsigned short u[8]; } pa, pb;
            pa.v4 = *reinterpret_cast<const int4*>(vp);
            pb.v4 = *reinterpret_cast<const int4*>(vp + 8);
            #pragma unroll
            for (int e = 0; e < 8; ++e) Vt[0][(vcol + e) * VTP + vxr]     = pa.u[e];
            #pragma unroll
            for (int e = 0; e < 8; ++e) Vt[0][(vcol + 8 + e) * VTP + vxr] = pb.u[e];
        }
        __syncthreads();

        for (int kt = 0; kt <= qt; ++kt) {
            const int b = kt & 1;
            union { int4 v4; unsigned short u[8]; } ua, ub;
            if (kt < qt) {
                const unsigned short* kp = k + (seqbase + (size_t)(kt + 1) * 64 + krow0) * rs
                                         + hd * HDIM + dreal;
                stage16(kp,                   &sK[b ^ 1][wave * 512],        lane);
                stage16(kp + (size_t)32 * rs, &sK[b ^ 1][2048 + wave * 512], lane);
                const unsigned short* vp = v + (seqbase + (size_t)(kt + 1) * 64 + vrow) * rs
                                         + hd * HDIM + vcol;
                ua.v4 = *reinterpret_cast<const int4*>(vp);
                ub.v4 = *reinterpret_cast<const int4*>(vp + 8);
            }

            f32x4 S[4];
            #pragma unroll
            for (int sub = 0; sub < 4; ++sub) {
                const unsigned short* kr = &sK[b][(sub * 16 + lr) * 64];
                bf16x8 b0 = *reinterpret_cast<const bf16x8*>(kr + ((quad * 8) ^ kswz));
                bf16x8 b1 = *reinterpret_cast<const bf16x8*>(kr + ((32 + quad * 8) ^ kswz));
                f32x4 accS = (f32x4){0.f, 0.f, 0.f, 0.f};
                accS = __builtin_amdgcn_mfma_f32_16x16x32_bf16(aQ0, b0, accS, 0, 0, 0);
                accS = __builtin_amdgcn_mfma_f32_16x16x32_bf16(aQ1, b1, accS, 0, 0, 0);
                S[sub] = accS;
            }
            const bool diag = (kt == qt);
            #pragma unroll
            for (int sub = 0; sub < 4; ++sub) {
                const int kg = kt * 64 + sub * 16 + lr;
                #pragma unroll
                for (int r = 0; r < 4; ++r) {
                    float s = S[sub][r] * C2;
                    if (diag && kg > q0 + quad * 4 + r) s = -__builtin_inff();
                    S[sub][r] = s;
                }
            }
            float mnew[4], alpha[4];
            #pragma unroll
            for (int r = 0; r < 4; ++r) {
                float mx = fmaxf(fmaxf(S[0][r], S[1][r]), fmaxf(S[2][r], S[3][r]));
                #pragma unroll
                for (int m = 1; m < 16; m <<= 1) mx = fmaxf(mx, __shfl_xor(mx, m));
                mnew[r]  = fmaxf(mrow[r], mx);
                alpha[r] = fexp2(mrow[r] - mnew[r]);
                mrow[r]  = mnew[r];
            }
            float rsum[4] = {0.f, 0.f, 0.f, 0.f};
            #pragma unroll
            for (int sub = 0; sub < 4; ++sub)
                #pragma unroll
                for (int r = 0; r < 4; ++r) {
                    float p = fexp2(S[sub][r] - mnew[r]);
                    S[sub][r] = p;
                    rsum[r] += p;
                }
            #pragma unroll
            for (int r = 0; r < 4; ++r) {
                float rs2 = rsum[r];
                #pragma unroll
                for (int m = 1; m < 16; m <<= 1) rs2 += __shfl_xor(rs2, m);
                lrow[r] = lrow[r] * alpha[r] + rs2;
            }

            #pragma unroll
            for (int sub = 0; sub < 4; ++sub)
                #pragma unroll
                for (int r = 0; r < 4; ++r) {
                    bf16_t hv = (bf16_t)S[sub][r];
                    Pw[(quad * 4 + r) * VTP + ((sub * 16 + lr) ^ (quad << 3))] =
                        *reinterpret_cast<unsigned short*>(&hv);
                }
            if (kt < qt) {
                #pragma unroll
                for (int e = 0; e < 8; ++e) Vt[b ^ 1][(vcol + e) * VTP + vxr]     = ua.u[e];
                #pragma unroll
                for (int e = 0; e < 8; ++e) Vt[b ^ 1][(vcol + 8 + e) * VTP + vxr] = ub.u[e];
            }
            #pragma unroll
            for (int d = 0; d < 4; ++d)
                #pragma unroll
                for (int r = 0; r < 4; ++r)
                    O[d][r] *= alpha[r];

            #pragma unroll
            for (int c = 0; c < 2; ++c) {
                bf16x8 aP = *reinterpret_cast<const bf16x8*>(
                    &Pw[lr * VTP + ((c * 32 + quad * 8) ^ pswr)]);
                #pragma unroll
                for (int d = 0; d < 4; ++d) {
                    bf16x8 bV = *reinterpret_cast<const bf16x8*>(
                        &Vt[b][(d * 16 + lr) * VTP + ((c * 32 + quad * 8) ^ (d << 4))]);
                    O[d] = __builtin_amdgcn_mfma_f32_16x16x32_bf16(aP, bV, O[d], 0, 0, 0);
                }
            }
            __syncthreads();
        }

        #pragma unroll
        for (int r = 0; r < 4; ++r) {
            const float rinv = 1.f / lrow[r];
            const int qg = q0 + quad * 4 + r;
            unsigned short* crow = ctx + (seqbase + qg) * EMB + hd * HDIM;
            #pragma unroll
            for (int d = 0; d < 4; ++d)
                crow[d * 16 + lr] = f2b(O[d][r] * rinv);
        }
    }
}

// ---------------------------------------------------------------------------
extern "C" void kernel_launch(void* const* d_in, const int* in_sizes, int n_in,
                              void* d_out, int out_size, void* d_ws, size_t ws_size,
                              hipStream_t stream) {
    const void* x  = d_in[0];
    const void* wq = d_in[1], *wk = d_in[2], *wv = d_in[3], *wo = d_in[4];
    const void* w1 = d_in[5], *w2 = d_in[6];
    const void* g1 = d_in[7], *s1 = d_in[8], *g2 = d_in[9], *s2 = d_in[10];
    char* ws = (char*)d_ws;
    dim3 blk(256);

    int* F = (int*)ws;
    {
        DetectArgs da;
        for (int i = 0; i < 11; ++i) { da.p[i] = (const unsigned short*)d_in[i]; da.n[i] = in_sizes[i]; }
        detect_all<<<11, blk, 0, stream>>>(da, F);
    }

    const size_t SZE = (size_t)MROWS * EMB;
    const size_t SZB = SZE * 2;
    unsigned short* base = (unsigned short*)(ws + 256);
    dim3 g768(MROWS / 128, EMB / 128);

    const size_t FULLB = 256 + 2ULL * (2 * W4E) + 2ULL * (4 * W2E)
                       + 2ULL * ((size_t)MROWS * 2304) + 2 * SZB
                       + 2ULL * ((size_t)MROWS * FFN);   // = 127,402,240 B
    const size_t FULLB2 = FULLB + 2ULL * SZE * 4;        // + 50.3 MB fp32 partials

    if (ws_size >= FULLB2) {
        // ---- full path + split-K FFN2 ----
        unsigned short* w1b   = base;
        unsigned short* w2b   = w1b + W4E;
        unsigned short* wqkvb = w2b + W4E;
        unsigned short* wob   = wqkvb + 3 * W2E;
        unsigned short* P     = wob + W2E;
        unsigned short* B0    = P + (size_t)MROWS * 2304;
        unsigned short* B1    = B0 + SZE;
        unsigned short* G     = B1 + SZE;
        float*          PK    = (float*)(G + (size_t)MROWS * FFN);

        {
            CvtArgs ca;
            ca.src[0] = wq; ca.src[1] = wk; ca.src[2] = wv;
            ca.src[3] = wo; ca.src[4] = w1; ca.src[5] = w2;
            ca.dst[0] = wqkvb; ca.dst[1] = wqkvb + W2E; ca.dst[2] = wqkvb + 2 * W2E;
            ca.dst[3] = wob;   ca.dst[4] = w1b;         ca.dst[5] = w2b;
            ca.n[0] = ca.n[1] = ca.n[2] = ca.n[3] = W2E; ca.n[4] = ca.n[5] = W4E;
            int off = 0;
            for (int s = 0; s < 6; ++s) { ca.blkoff[s] = off; off += ca.n[s] / 1024; }
            ca.blkoff[6] = off;
            ca.F = F;
            ca.fidx[0] = 1; ca.fidx[1] = 2; ca.fidx[2] = 3;
            ca.fidx[3] = 4; ca.fidx[4] = 5; ca.fidx[5] = 6;
            cvt_weights<<<off, blk, 0, stream>>>(ca);
        }

        ln_kernel<<<MROWS / 4, blk, 0, stream>>>(x, F+0, g1, F+7, s1, F+8, B1);
        dim3 gqkv(MROWS / 128, 2304 / 128);
        gemm_lds<false, false, false><<<gqkv, blk, 0, stream>>>(B1, wqkvb, nullptr, nullptr, 0, P, MROWS, 2304, EMB, EMB, EMB);
        fattn_kernel<<<BATCH * NHEADS * 8, blk, 0, stream>>>(P, P + 768, P + 1536, 2304, B0);
        gemm_lds<false, true, false><<<g768, blk, 0, stream>>>(B0, wob, x, F+0, 0, B1, MROWS, EMB, EMB, EMB, EMB);
        ln_kernel<<<MROWS / 4, blk, 0, stream>>>(B1, nullptr, g2, F+9, s2, F+10, B0);
        dim3 gffn1(MROWS / 128, FFN / 128);
        gemm_lds<true, false, false><<<gffn1, blk, 0, stream>>>(B0, w1b, nullptr, nullptr, 0, G, MROWS, FFN, EMB, EMB, EMB);
        dim3 gsk(MROWS / 128, EMB / 128, 2);
        gemm_lds<false, false, true><<<gsk, blk, 0, stream>>>(G, w2b, nullptr, nullptr, 0, PK, MROWS, EMB, FFN / 2, FFN, FFN);
        reduce2_kernel<<<(SZE / 4 + 255) / 256, blk, 0, stream>>>(PK, B1, (float*)d_out, SZE / 4);
    } else if (ws_size >= FULLB) {
        // ---- full path, single-launch FFN2 ----
        unsigned short* w1b   = base;
        unsigned short* w2b   = w1b + W4E;
        unsigned short* wqkvb = w2b + W4E;
        unsigned short* wob   = wqkvb + 3 * W2E;
        unsigned short* P     = wob + W2E;
        unsigned short* B0    = P + (size_t)MROWS * 2304;
        unsigned short* B1    = B0 + SZE;
        unsigned short* G     = B1 + SZE;

        {
            CvtArgs ca;
            ca.src[0] = wq; ca.src[1] = wk; ca.src[2] = wv;
            ca.src[3] = wo; ca.src[4] = w1; ca.src[5] = w2;
            ca.dst[0] = wqkvb; ca.dst[1] = wqkvb + W2E; ca.dst[2] = wqkvb + 2 * W2E;
            ca.dst[3] = wob;   ca.dst[4] = w1b;         ca.dst[5] = w2b;
            ca.n[0] = ca.n[1] = ca.n[2] = ca.n[3] = W2E; ca.n[4] = ca.n[5] = W4E;
            int off = 0;
            for (int s = 0; s < 6; ++s) { ca.blkoff[s] = off; off += ca.n[s] / 1024; }
            ca.blkoff[6] = off;
            ca.F = F;
            ca.fidx[0] = 1; ca.fidx[1] = 2; ca.fidx[2] = 3;
            ca.fidx[3] = 4; ca.fidx[4] = 5; ca.fidx[5] = 6;
            cvt_weights<<<off, blk, 0, stream>>>(ca);
        }

        ln_kernel<<<MROWS / 4, blk, 0, stream>>>(x, F+0, g1, F+7, s1, F+8, B1);
        dim3 gqkv(MROWS / 128, 2304 / 128);
        gemm_lds<false, false, false><<<gqkv, blk, 0, stream>>>(B1, wqkvb, nullptr, nullptr, 0, P, MROWS, 2304, EMB, EMB, EMB);
        fattn_kernel<<<BATCH * NHEADS * 8, blk, 0, stream>>>(P, P + 768, P + 1536, 2304, B0);
        gemm_lds<false, true, false><<<g768, blk, 0, stream>>>(B0, wob, x, F+0, 0, B1, MROWS, EMB, EMB, EMB, EMB);
        ln_kernel<<<MROWS / 4, blk, 0, stream>>>(B1, nullptr, g2, F+9, s2, F+10, B0);
        dim3 gffn1(MROWS / 128, FFN / 128);
        gemm_lds<true, false, false><<<gffn1, blk, 0, stream>>>(B0, w1b, nullptr, nullptr, 0, G, MROWS, FFN, EMB, EMB, EMB);
        gemm_lds<false, true, true><<<g768, blk, 0, stream>>>(G, w2b, B1, nullptr, 0, d_out, MROWS, EMB, FFN, FFN, FFN);
    } else if (ws_size >= 256 + 4 * SZB) {
        // ---- fallback tier M ----
        unsigned short* B0 = base;
        unsigned short* B1 = B0 + SZE;
        unsigned short* B2 = B1 + SZE;
        unsigned short* B3 = B2 + SZE;
        ln_kernel<<<MROWS / 4, blk, 0, stream>>>(x, F+0, g1, F+7, s1, F+8, B0);
        gemm_bt<false, false, false><<<g768, blk, 0, stream>>>(B0, wq, F+1, nullptr, nullptr, 0, B1, MROWS, EMB, EMB);
        gemm_bt<false, false, false><<<g768, blk, 0, stream>>>(B0, wk, F+2, nullptr, nullptr, 0, B2, MROWS, EMB, EMB);
        gemm_bt<false, false, false><<<g768, blk, 0, stream>>>(B0, wv, F+3, nullptr, nullptr, 0, B3, MROWS, EMB, EMB);
        fattn_kernel<<<BATCH * NHEADS * 8, blk, 0, stream>>>(B1, B2, B3, EMB, B0);
        gemm_bt<false, true, false><<<g768, blk, 0, stream>>>(B0, wo, F+4, x, F+0, 0, B1, MROWS, EMB, EMB);
        ln_kernel<<<MROWS / 4, blk, 0, stream>>>(B1, nullptr, g2, F+9, s2, F+10, B2);
        dim3 c3072(2048 / 128, FFN / 128), c768(2048 / 128, EMB / 128);
        for (int c = 0; c < 4; ++c) {
            const size_t r0 = (size_t)c * 2048;
            gemm_bt<true, false, false><<<c3072, blk, 0, stream>>>(B2 + r0 * EMB, w1, F+5, nullptr, nullptr, 0, B3, 2048, FFN, EMB);
            gemm_bt<false, true, true><<<c768, blk, 0, stream>>>(B3, w2, F+6, B1 + r0 * EMB, nullptr, 0, (float*)d_out + r0 * EMB, 2048, EMB, FFN);
        }
    } else {
        // ---- fallback tier B ----
        unsigned short* hlow = (unsigned short*)d_out;
        unsigned short* x2up = (unsigned short*)d_out + SZE;
        unsigned short* wsQ = base;
        unsigned short* wsK = wsQ + (size_t)1024 * EMB;
        unsigned short* wsV = wsK + (size_t)1024 * EMB;
        unsigned short* wsC = wsV + (size_t)1024 * EMB;
        ln_kernel<<<MROWS / 4, blk, 0, stream>>>(x, F+0, g1, F+7, s1, F+8, hlow);
        dim3 q768(1024 / 128, EMB / 128);
        for (int grp = 0; grp < BATCH; ++grp) {
            const size_t r0 = (size_t)grp * 1024;
            gemm_bt<false, false, false><<<q768, blk, 0, stream>>>(hlow + r0 * EMB, wq, F+1, nullptr, nullptr, 0, wsQ, 1024, EMB, EMB);
            gemm_bt<false, false, false><<<q768, blk, 0, stream>>>(hlow + r0 * EMB, wk, F+2, nullptr, nullptr, 0, wsK, 1024, EMB, EMB);
            gemm_bt<false, false, false><<<q768, blk, 0, stream>>>(hlow + r0 * EMB, wv, F+3, nullptr, nullptr, 0, wsV, 1024, EMB, EMB);
            fattn_kernel<<<1 * NHEADS * 8, blk, 0, stream>>>(wsQ, wsK, wsV, EMB, wsC);
            gemm_bt<false, true, false><<<q768, blk, 0, stream>>>(wsC, wo, F+4, x, F+0, r0 * EMB, x2up + r0 * EMB, 1024, EMB, EMB);
        }
        unsigned short* xb = base;
        unsigned short* h2 = xb + (size_t)1024 * EMB;
        unsigned short* gb = h2 + (size_t)1024 * EMB;
        dim3 f3072(1024 / 128, FFN / 128), f768(1024 / 128, EMB / 128);
        for (int c = 0; c < BATCH; ++c) {
            const size_t r0 = (size_t)c * 1024;
            hipMemcpyAsync(xb, x2up + r0 * EMB, (size_t)1024 * EMB * 2,
                           hipMemcpyDeviceToDevice, stream);
            ln_kernel<<<1024 / 4, blk, 0, stream>>>(xb, nullptr, g2, F+9, s2, F+10, h2);
            gemm_bt<true, false, false><<<f3072, blk, 0, stream>>>(h2, w1, F+5, nullptr, nullptr, 0, gb, 1024, FFN, EMB);
            gemm_bt<false, true, true><<<f768, blk, 0, stream>>>(gb, w2, F+6, xb, nullptr, 0, (float*)d_out + r0 * EMB, 1024, EMB, FFN);
        }
    }
}